// Round 21
// baseline (43.646 us; speedup 1.0000x reference)
//
#include <hip/hip_runtime.h>
#include <hip/hip_bf16.h>

// ShuffleNet fused block-MLP, MI355X (gfx950).  R21 = R20 + np-PAIR WGs:
// 1024-thr WG stages TWO np weight slices (144 KB LDS, allowed: 160 KB/WG on
// gfx950 per AITER attn) -> xT re-read halves (256->128 MB L2), staging BW
// amortized over 2x compute. Decode keeps XCD alignment (R20's -5us win):
//   x_ = b&7, pr = (b>>3)&7, ghi = b>>6;  g = ghi*8 + x_;
//   wave wv: np = pr*2 + (wv>>3), rt = (wv&7)*64 + g  -> rt = x_ (mod 8)
//   = block XCD = pack_x writer XCD for that rt.
// Math = R11..R20 (passed, absmax 9.77e-4): pi-permuted w2 pack makes GEMM2's
// A-frag the lane's own GEMM1 outputs; pi(k)=32*(k>>5)+16*((k>>2)&1)+4*((k>>3)&3)+(k&3).
// xT frag (rt,n,ks): lane l elem e = bf16(x[rt*16+(l&15)][n*64+ks*32+(l>>4)*8+e])
//   at xT[((rt*16+n)*2+ks)*512 + l*8 + e].

typedef __attribute__((ext_vector_type(8))) short  short8;   // 8 bf16 = 4 VGPR
typedef __attribute__((ext_vector_type(4))) short  short4v;
typedef __attribute__((ext_vector_type(4))) float  floatx4;

#define XP 1032   // pack_x LDS row pitch (516 dw = 4 mod 32 -> bank rotation)

__device__ __forceinline__ short f2bf(float f) {
  union { __hip_bfloat16 h; short s; } u;
  u.h = __float2bfloat16(f);
  return u.s;
}
__device__ __forceinline__ float bf2f(short s) {
  union { float f; unsigned u; } uu;
  uu.u = ((unsigned)(unsigned short)s) << 16;
  return uu.f;
}
__device__ __forceinline__ int pk16(float a, float b) {
  return (int)(unsigned short)f2bf(a) | ((int)(unsigned short)f2bf(b) << 16);
}

// gelu(v) ~= v * sigmoid(1.5957691*(v + 0.044715 v^3)), exp2-folded (abs<5e-4)
__device__ __forceinline__ float gelu_f(float v) {
  float m = v * v;
  float c = fmaf(-0.1029375f, m, -2.3020807f);
  float z = v * c;
  float e = __builtin_amdgcn_exp2f(z);
  return v * __builtin_amdgcn_rcpf(1.0f + e);
}

// ---- pack kernel: w1 frags | w2 frags (pi-permuted) | b1 frags (bf16) ----
__global__ void pack_k(const float* __restrict__ w1, const float* __restrict__ w2,
                       const float* __restrict__ b1, short* __restrict__ w1p,
                       short* __restrict__ w2p, short* __restrict__ b1p) {
  const int t = blockIdx.x * blockDim.x + threadIdx.x;  // 160*512 = 81920
  const int lane = t & 63;
  const int lhi = lane >> 4;
  if (t < 32768) {  // w1 frag (n,np,ks): lane l elem e = w1[n][np*16+(l&15)][ks*32+lhi*8+e]
    const int ks = (t >> 6) & 1, np = (t >> 7) & 15, n = (t >> 11) & 15;
    const float* src = w1 + ((size_t)(n * 256 + np * 16 + (lane & 15)) * 64 + ks * 32 + lhi * 8);
    short8 f;
#pragma unroll
    for (int e = 0; e < 8; ++e) f[e] = f2bf(src[e]);
    *(short8*)(w1p + (size_t)t * 8) = f;
  } else if (t < 65536) {  // w2 frag (np,s,ot), pi-permuted k
    const int t2 = t - 32768;
    const int ot = (t2 >> 6) & 3, s = (t2 >> 8) & 7, np = (t2 >> 11) & 15;
    const int op = ot * 16 + (lane & 15);
    short8 f;
#pragma unroll
    for (int e = 0; e < 8; ++e) {
      const int Kc = 32 * s + 16 * ((e >> 2) & 1) + 4 * lhi + (e & 3);
      const int n = Kc >> 4, ohi = Kc & 15;
      f[e] = f2bf(w2[(size_t)(np * 64 + op) * 256 + ohi * 16 + n]);
    }
    *(short8*)(w2p + (size_t)t2 * 8) = f;
  } else {  // b1 frag (n,np): lane l reg r = bf16(b1[(np*16+lhi*4+r)*16+n])
    const int t3 = t - 65536;  // 16384
    const int np = (t3 >> 6) & 15, n = (t3 >> 10) & 15;
    short4v b;
#pragma unroll
    for (int r = 0; r < 4; ++r) b[r] = f2bf(b1[(np * 16 + lhi * 4 + r) * 16 + n]);
    *(short4v*)(b1p + (size_t)((n * 16 + np) * 64 + lane) * 4) = b;
  }
}

// ---- pack_x: LDS-staged transpose; block g -> rt g (XCD g&7). 512 x 256. ----
__global__ __launch_bounds__(256, 4) void pack_x(
    const float* __restrict__ x, short* __restrict__ xT) {
  __shared__ __align__(16) short xs[16 * XP];
  const int tid = threadIdx.x;
  const int wv = tid >> 6, lane = tid & 63;
  const int l15 = lane & 15, lhi = lane >> 4;
  const int rt = blockIdx.x;

#pragma unroll
  for (int j = 0; j < 16; ++j) {
    floatx4 v = __builtin_nontemporal_load(
        (const floatx4*)(x + (size_t)(rt * 16 + j) * 1024 + tid * 4));
    short4v s;
#pragma unroll
    for (int e = 0; e < 4; ++e) s[e] = f2bf(v[e]);
    *(short4v*)(&xs[j * XP + tid * 4]) = s;
  }
  __syncthreads();

#pragma unroll
  for (int i = 0; i < 8; ++i) {
    const int f = wv * 8 + i, n = f >> 1, ks = f & 1;
    short8 fr = *(const short8*)(&xs[l15 * XP + n * 64 + ks * 32 + lhi * 8]);
    *(short8*)(xT + ((size_t)(rt * 16 + n) * 2 + ks) * 512 + lane * 8) = fr;
  }
}

// x-frag load macro (named regs; the only global loads in the hot loop)
#define XLOAD(P0, P1, P2, P3, ss) {                                            \
  const int n0_ = 2 * (ss), n1_ = n0_ + 1;                                     \
  P0 = *(const short8*)(xT + ((size_t)(rt * 16 + n0_) * 2 + 0) * 512 + lane * 8); \
  P1 = *(const short8*)(xT + ((size_t)(rt * 16 + n0_) * 2 + 1) * 512 + lane * 8); \
  P2 = *(const short8*)(xT + ((size_t)(rt * 16 + n1_) * 2 + 0) * 512 + lane * 8); \
  P3 = *(const short8*)(xT + ((size_t)(rt * 16 + n1_) * 2 + 1) * 512 + lane * 8); \
}

// ---- fused: 512 WGs x 1024 thr (16 waves); np-pair in 144 KB LDS ----
__global__ __launch_bounds__(1024, 1) void fused_k(
    const short* __restrict__ xT, const short* __restrict__ w1p,
    const short* __restrict__ w2p, const short* __restrict__ b1p,
    const float* __restrict__ b2, float* __restrict__ y) {
  __shared__ __align__(16) short lw1[2 * 16384];  // 64 KB: w1, 2 np-slices
  __shared__ __align__(16) short lw2[2 * 16384];  // 64 KB: w2, 2 np-slices
  __shared__ __align__(16) short lb1[2 * 4096];   // 16 KB: b1, 2 np-slices

  const int tid = threadIdx.x;
  const int wv = tid >> 6, lane = tid & 63;
  const int l15 = lane & 15, lhi = lane >> 4;
  const int x_  = blockIdx.x & 7;          // XCD
  const int pr  = (blockIdx.x >> 3) & 7;   // np-pair 0..7
  const int ghi = blockIdx.x >> 6;         // 0..7
  const int g   = ghi * 8 + x_;            // 0..63 ; g&7 == XCD
  const int npi = wv >> 3;                 // 0..1
  const int np  = pr * 2 + npi;
  const int rt  = (wv & 7) * 64 + g;       // rt&7 == XCD == pack_x writer

  // ---- stage BOTH np slices (coalesced; 1024 threads) ----
#pragma unroll
  for (int i = 0; i < 4; ++i) {            // lw1: 4096 short8 (2 x 2048)
    const int u = i * 1024 + tid;
    const int sl = u >> 11, v = u & 2047;  // slice, idx
    const int c = v >> 6, e = v & 63;      // chunk c = n*2+ks
    const int np_s = pr * 2 + sl;
    const size_t so = (((size_t)(c >> 1) * 16 + np_s) * 2 + (c & 1)) * 512 + e * 8;
    *(short8*)(&lw1[sl * 16384 + c * 512 + e * 8]) = *(const short8*)(w1p + so);
  }
#pragma unroll
  for (int i = 0; i < 4; ++i) {            // lw2: 4096 short8, contiguous slices
    const int u = i * 1024 + tid;
    const int sl = u >> 11, v = u & 2047;
    const int np_s = pr * 2 + sl;
    *(short8*)(&lw2[sl * 16384 + v * 8]) =
        *(const short8*)(w2p + (size_t)np_s * 16384 + v * 8);
  }
  {                                        // lb1: 1024 short8 (2 x 512)
    const int sl = tid >> 9, v = tid & 511;
    const int n = v >> 5, e = v & 31;
    const int np_s = pr * 2 + sl;
    *(short8*)(&lb1[sl * 4096 + n * 256 + e * 8]) =
        *(const short8*)(b1p + (size_t)(n * 16 + np_s) * 256 + e * 8);
  }
  __syncthreads();   // the only barrier

  const short* W1 = lw1 + npi * 16384;     // wave-uniform LDS bases
  const short* W2 = lw2 + npi * 16384;
  const short* B1 = lb1 + npi * 4096;

  floatx4 c0 = {0.f,0.f,0.f,0.f}, c1 = {0.f,0.f,0.f,0.f};
  floatx4 c2 = {0.f,0.f,0.f,0.f}, c3 = {0.f,0.f,0.f,0.f};

  short8 xA0, xA1, xA2, xA3, xB0, xB1, xB2, xB3;
  XLOAD(xA0, xA1, xA2, xA3, 0)

#pragma unroll
  for (int s = 0; s < 8; ++s) {
    if (s < 7) {                           // issue-early prefetch of step s+1
      if (s & 1) { XLOAD(xA0, xA1, xA2, xA3, s + 1) }
      else       { XLOAD(xB0, xB1, xB2, xB3, s + 1) }
    }
    const short8 xf00 = (s & 1) ? xB0 : xA0;   // n = 2s,   ks = 0
    const short8 xf01 = (s & 1) ? xB1 : xA1;   // n = 2s,   ks = 1
    const short8 xf10 = (s & 1) ? xB2 : xA2;   // n = 2s+1, ks = 0
    const short8 xf11 = (s & 1) ? xB3 : xA3;   // n = 2s+1, ks = 1

    union { int i[4]; short8 v; } af;
    {
      const int n = 2 * s;
      short8 wf0 = *(const short8*)(&W1[(n * 2 + 0) * 512 + lane * 8]);
      short8 wf1 = *(const short8*)(&W1[(n * 2 + 1) * 512 + lane * 8]);
      short4v bv = *(const short4v*)(&B1[n * 256 + lane * 4]);
      floatx4 acc = {0.f, 0.f, 0.f, 0.f};
      acc = __builtin_amdgcn_mfma_f32_16x16x32_bf16(wf0, xf00, acc, 0, 0, 0);
      acc = __builtin_amdgcn_mfma_f32_16x16x32_bf16(wf1, xf01, acc, 0, 0, 0);
      af.i[0] = pk16(gelu_f(acc[0] + bf2f(bv[0])), gelu_f(acc[1] + bf2f(bv[1])));
      af.i[1] = pk16(gelu_f(acc[2] + bf2f(bv[2])), gelu_f(acc[3] + bf2f(bv[3])));
    }
    {
      const int n = 2 * s + 1;
      short8 wf0 = *(const short8*)(&W1[(n * 2 + 0) * 512 + lane * 8]);
      short8 wf1 = *(const short8*)(&W1[(n * 2 + 1) * 512 + lane * 8]);
      short4v bv = *(const short4v*)(&B1[n * 256 + lane * 4]);
      floatx4 acc = {0.f, 0.f, 0.f, 0.f};
      acc = __builtin_amdgcn_mfma_f32_16x16x32_bf16(wf0, xf10, acc, 0, 0, 0);
      acc = __builtin_amdgcn_mfma_f32_16x16x32_bf16(wf1, xf11, acc, 0, 0, 0);
      af.i[2] = pk16(gelu_f(acc[0] + bf2f(bv[0])), gelu_f(acc[1] + bf2f(bv[1])));
      af.i[3] = pk16(gelu_f(acc[2] + bf2f(bv[2])), gelu_f(acc[3] + bf2f(bv[3])));
    }

    // GEMM2 slice s: A-frag = lane's own registers (pi-fold); B from LDS
    short8 bf0  = *(const short8*)(&W2[(s * 4 + 0) * 512 + lane * 8]);
    short8 bf1  = *(const short8*)(&W2[(s * 4 + 1) * 512 + lane * 8]);
    short8 bf2v = *(const short8*)(&W2[(s * 4 + 2) * 512 + lane * 8]);
    short8 bf3  = *(const short8*)(&W2[(s * 4 + 3) * 512 + lane * 8]);
    c0 = __builtin_amdgcn_mfma_f32_16x16x32_bf16(af.v, bf0,  c0, 0, 0, 0);
    c1 = __builtin_amdgcn_mfma_f32_16x16x32_bf16(af.v, bf1,  c1, 0, 0, 0);
    c2 = __builtin_amdgcn_mfma_f32_16x16x32_bf16(af.v, bf2v, c2, 0, 0, 0);
    c3 = __builtin_amdgcn_mfma_f32_16x16x32_bf16(af.v, bf3,  c3, 0, 0, 0);
  }

  // ---- y store (NT): col = np*64 + ot*16 + l15, rows rt*16 + lhi*4 + r ----
  floatx4 cc[4] = {c0, c1, c2, c3};
#pragma unroll
  for (int ot = 0; ot < 4; ++ot) {
    const int col = np * 64 + ot * 16 + l15;
    const float bb = b2[col];
    float* py = y + (size_t)(rt * 16 + lhi * 4) * 1024 + col;
#pragma unroll
    for (int r = 0; r < 4; ++r)
      __builtin_nontemporal_store(cc[ot][r] + bb, py + (size_t)r * 1024);
  }
}

extern "C" void kernel_launch(void* const* d_in, const int* in_sizes, int n_in,
                              void* d_out, int out_size, void* d_ws, size_t ws_size,
                              hipStream_t stream) {
  const float* x  = (const float*)d_in[0];
  const float* w1 = (const float*)d_in[1];
  const float* b1 = (const float*)d_in[2];
  const float* w2 = (const float*)d_in[3];
  const float* b2 = (const float*)d_in[4];
  float* y = (float*)d_out;

  short* w1p = (short*)d_ws;               // 512 KB
  short* w2p = w1p + 16 * 256 * 64;        // 512 KB
  short* b1p = w2p + 16 * 256 * 64;        // 128 KB
  short* xT  = b1p + 16 * 16 * 64 * 4;     // 16 MB (bf16 fragment-order x)

  pack_k<<<160, 512, 0, stream>>>(w1, w2, b1, w1p, w2p, b1p);
  pack_x<<<512, 256, 0, stream>>>(x, xT);
  fused_k<<<512, 1024, 0, stream>>>(xT, w1p, w2p, b1p, b2, y);
}